// Round 1
// baseline (147.870 us; speedup 1.0000x reference)
//
#include <hip/hip_runtime.h>

typedef __attribute__((ext_vector_type(8))) short short8;
typedef __attribute__((ext_vector_type(4))) float f32x4;

#define EPSF 1e-5f
#define NSEQ 4096
#define R_TOT 8192

__device__ __forceinline__ float bf2f(unsigned short u){
  union { unsigned int i; float f; } v; v.i = ((unsigned int)u) << 16; return v.f;
}
__device__ __forceinline__ unsigned short f2bf(float f){
  union { float f; unsigned int i; } v; v.f = f;
  unsigned int u = v.i;
  u += 0x7FFFu + ((u >> 16) & 1u);          // RNE
  return (unsigned short)(u >> 16);
}
__device__ __forceinline__ float wsum(float v){
  #pragma unroll
  for (int o = 32; o > 0; o >>= 1) v += __shfl_xor(v, o, 64);
  return v;
}
__device__ __forceinline__ float wmax(float v){
  #pragma unroll
  for (int o = 32; o > 0; o >>= 1) v = fmaxf(v, __shfl_xor(v, o, 64));
  return v;
}
__device__ __forceinline__ float gelu_tanh(float x){
  float x3 = x * x * x;
  return 0.5f * x * (1.0f + tanhf(0.7978845608028654f * (x + 0.044715f * x3)));
}

// ---------------- fp32 -> bf16 convert (vectorized) ----------------
__global__ void k_f2bf(const float* __restrict__ in, unsigned short* __restrict__ out, int n){
  int i = (blockIdx.x * 256 + threadIdx.x) * 4;
  if (i < n){
    float4 v = *(const float4*)(in + i);
    ushort4 o;
    o.x = f2bf(v.x); o.y = f2bf(v.y); o.z = f2bf(v.z); o.w = f2bf(v.w);
    *(ushort4*)(out + i) = o;
  }
}

// ---------------- transpose + convert: out[c][r] = in[r][c] ----------------
__global__ void k_transpose_bf(const float* __restrict__ in, unsigned short* __restrict__ out,
                               int rows, int cols){
  int idx = blockIdx.x * 256 + threadIdx.x;   // output-linear: idx = c*rows + r
  if (idx < rows * cols){
    int c = idx / rows, r = idx - c * rows;
    out[idx] = f2bf(in[(size_t)r * cols + c]);
  }
}

// ---------------- bf16 MFMA GEMM: C[M,N] = A[M,K] @ BT[N,K]^T ----------------
template<bool HAS_BIAS, bool DO_GELU, bool OUT_BF16>
__global__ void k_gemm(const unsigned short* __restrict__ A,
                       const unsigned short* __restrict__ BT,
                       const float* __restrict__ bias,
                       float* __restrict__ Cf,
                       unsigned short* __restrict__ Cb,
                       int M, int N, int K)
{
  const int BM = 128, BN = 128, BK = 64, LDSS = 72;   // +8 bf16 pad: 144B row stride
  __shared__ unsigned short As[128 * 72];
  __shared__ unsigned short Bs[128 * 72];
  const int t  = threadIdx.x;
  const int l  = t & 63;
  const int w  = t >> 6;
  const int wm = w >> 1, wn = w & 1;
  const int lr = l & 15, kq = l >> 4;
  const int m0 = blockIdx.y * BM, n0 = blockIdx.x * BN;

  f32x4 acc[4][4];
  #pragma unroll
  for (int i = 0; i < 4; i++)
    #pragma unroll
    for (int j = 0; j < 4; j++) acc[i][j] = (f32x4){0.f, 0.f, 0.f, 0.f};

  const int srow = t >> 1, scol = (t & 1) * 32;
  const unsigned short* Ag = A  + (size_t)(m0 + srow) * K + scol;
  const unsigned short* Bg = BT + (size_t)(n0 + srow) * K + scol;
  unsigned short* Asw = &As[srow * LDSS + scol];
  unsigned short* Bsw = &Bs[srow * LDSS + scol];

  for (int k0 = 0; k0 < K; k0 += BK){
    short8 a0 = *(const short8*)(Ag);      short8 a1 = *(const short8*)(Ag + 8);
    short8 a2 = *(const short8*)(Ag + 16); short8 a3 = *(const short8*)(Ag + 24);
    short8 b0 = *(const short8*)(Bg);      short8 b1 = *(const short8*)(Bg + 8);
    short8 b2 = *(const short8*)(Bg + 16); short8 b3 = *(const short8*)(Bg + 24);
    *(short8*)(Asw)      = a0; *(short8*)(Asw + 8)  = a1;
    *(short8*)(Asw + 16) = a2; *(short8*)(Asw + 24) = a3;
    *(short8*)(Bsw)      = b0; *(short8*)(Bsw + 8)  = b1;
    *(short8*)(Bsw + 16) = b2; *(short8*)(Bsw + 24) = b3;
    __syncthreads();
    #pragma unroll
    for (int kk = 0; kk < BK; kk += 32){
      short8 af[4], bfr[4];
      #pragma unroll
      for (int i = 0; i < 4; i++)
        af[i]  = *(const short8*)&As[(wm * 64 + i * 16 + lr) * LDSS + kk + kq * 8];
      #pragma unroll
      for (int j = 0; j < 4; j++)
        bfr[j] = *(const short8*)&Bs[(wn * 64 + j * 16 + lr) * LDSS + kk + kq * 8];
      #pragma unroll
      for (int i = 0; i < 4; i++)
        #pragma unroll
        for (int j = 0; j < 4; j++)
          acc[i][j] = __builtin_amdgcn_mfma_f32_16x16x32_bf16(af[i], bfr[j], acc[i][j], 0, 0, 0);
    }
    __syncthreads();
    Ag += BK; Bg += BK;
  }

  const int row0 = m0 + wm * 64;
  const int col0 = n0 + wn * 64;
  #pragma unroll
  for (int i = 0; i < 4; i++){
    #pragma unroll
    for (int j = 0; j < 4; j++){
      #pragma unroll
      for (int r = 0; r < 4; r++){
        int row = row0 + i * 16 + kq * 4 + r;
        int col = col0 + j * 16 + lr;
        float v = acc[i][j][r];
        if (HAS_BIAS) v += bias[col];
        if (DO_GELU)  v = gelu_tanh(v);
        if (OUT_BF16) Cb[(size_t)row * N + col] = f2bf(v);
        else          Cf[(size_t)row * N + col] = v;
      }
    }
  }
}

// ---------------- softmax stats over sequence per (b,h,e) column ----------------
__global__ void k_smax(const unsigned short* __restrict__ qkv,
                       float* __restrict__ kmax, float* __restrict__ kinv)
{
  const int cid = blockIdx.x;            // b*256 + h*64 + e
  const int b = cid >> 8;
  const int he = cid & 255;
  const unsigned short* base = qkv + (size_t)b * NSEQ * 768 + 256 + he;
  const int t = threadIdx.x;
  float vals[16];
  float mx = -3.4e38f;
  #pragma unroll
  for (int i = 0; i < 16; i++){
    vals[i] = bf2f(base[(size_t)(i * 256 + t) * 768]);
    mx = fmaxf(mx, vals[i]);
  }
  mx = wmax(mx);
  __shared__ float redm[4], reds[4];
  if ((t & 63) == 0) redm[t >> 6] = mx;
  __syncthreads();
  mx = fmaxf(fmaxf(redm[0], redm[1]), fmaxf(redm[2], redm[3]));
  float s = 0.f;
  #pragma unroll
  for (int i = 0; i < 16; i++) s += expf(vals[i] - mx);
  s = wsum(s);
  if ((t & 63) == 0) reds[t >> 6] = s;
  __syncthreads();
  s = reds[0] + reds[1] + reds[2] + reds[3];
  if (t == 0){ kmax[cid] = mx; kinv[cid] = 1.0f / s; }
}

// ---------------- M partials: M[e,d] = sum_n softmax(k)[n,e] * q[n,d] ----------------
__global__ void k_mpart(const unsigned short* __restrict__ qkv,
                        const float* __restrict__ kmax, const float* __restrict__ kinv,
                        float* __restrict__ Mpart)
{
  const int s  = blockIdx.x;   // k-slice 0..15 (256 rows each)
  const int bh = blockIdx.y;   // 0..7
  const int b = bh >> 2, h = bh & 3;
  const int t = threadIdx.x;
  __shared__ float ks[16][64], qs[16][64];
  __shared__ float mxs[64], ivs[64];
  if (t < 64){ mxs[t] = kmax[bh * 64 + t]; ivs[t] = kinv[bh * 64 + t]; }
  const int e = t & 63, dg = t >> 6;        // thread computes M[e][dg*16 .. dg*16+15]
  const int r = t >> 4, c4 = (t & 15) * 4;  // staging coords
  float acc[16];
  #pragma unroll
  for (int i = 0; i < 16; i++) acc[i] = 0.f;

  for (int ch = 0; ch < 16; ch++){
    int n = s * 256 + ch * 16 + r;
    const unsigned short* rowp = qkv + (size_t)(b * NSEQ + n) * 768 + h * 64 + c4;
    ushort4 qv = *(const ushort4*)(rowp);
    ushort4 kv = *(const ushort4*)(rowp + 256);
    __syncthreads();            // prev accumulate done (and stats visible on ch==0)
    qs[r][c4 + 0] = bf2f(qv.x); qs[r][c4 + 1] = bf2f(qv.y);
    qs[r][c4 + 2] = bf2f(qv.z); qs[r][c4 + 3] = bf2f(qv.w);
    ks[r][c4 + 0] = expf(bf2f(kv.x) - mxs[c4 + 0]) * ivs[c4 + 0];
    ks[r][c4 + 1] = expf(bf2f(kv.y) - mxs[c4 + 1]) * ivs[c4 + 1];
    ks[r][c4 + 2] = expf(bf2f(kv.z) - mxs[c4 + 2]) * ivs[c4 + 2];
    ks[r][c4 + 3] = expf(bf2f(kv.w) - mxs[c4 + 3]) * ivs[c4 + 3];
    __syncthreads();
    #pragma unroll
    for (int rr = 0; rr < 16; rr++){
      float kvv = ks[rr][e];
      const float4* qp = (const float4*)&qs[rr][dg * 16];
      float4 q0 = qp[0], q1 = qp[1], q2 = qp[2], q3 = qp[3];
      acc[0]  += kvv * q0.x; acc[1]  += kvv * q0.y; acc[2]  += kvv * q0.z; acc[3]  += kvv * q0.w;
      acc[4]  += kvv * q1.x; acc[5]  += kvv * q1.y; acc[6]  += kvv * q1.z; acc[7]  += kvv * q1.w;
      acc[8]  += kvv * q2.x; acc[9]  += kvv * q2.y; acc[10] += kvv * q2.z; acc[11] += kvv * q2.w;
      acc[12] += kvv * q3.x; acc[13] += kvv * q3.y; acc[14] += kvv * q3.z; acc[15] += kvv * q3.w;
    }
  }
  float* outp = Mpart + (size_t)(s * 8 + bh) * 4096 + e * 64 + dg * 16;
  #pragma unroll
  for (int i = 0; i < 16; i++) outp[i] = acc[i];
}

// ---------------- reduce 16 K-slices, apply SCALE=0.125 ----------------
__global__ void k_mreduce(const float* __restrict__ Mpart, float* __restrict__ M){
  int idx = blockIdx.x * 256 + threadIdx.x;   // [0, 8*4096)
  float s = 0.f;
  #pragma unroll
  for (int sl = 0; sl < 16; sl++) s += Mpart[(size_t)sl * 32768 + idx];
  M[idx] = s * 0.125f;
}

// ---------------- out = v @ M, written in the torch-reshape layout, bf16 ----------------
__global__ void k_vm(const unsigned short* __restrict__ qkv,
                     const float* __restrict__ M,
                     unsigned short* __restrict__ attn)
{
  const int bh = blockIdx.y, b = bh >> 2, h = bh & 3;
  const int t = threadIdx.x;
  __shared__ float Ms[64 * 64];
  __shared__ float vs[16][64];
  #pragma unroll
  for (int i = 0; i < 16; i++) Ms[i * 256 + t] = M[(size_t)bh * 4096 + i * 256 + t];
  const int r = t >> 4, c4 = (t & 15) * 4;
  const int n = blockIdx.x * 16 + r;
  const unsigned short* vp = qkv + (size_t)(b * NSEQ + n) * 768 + 512 + h * 64 + c4;
  ushort4 vv = *(const ushort4*)vp;
  vs[r][c4 + 0] = bf2f(vv.x); vs[r][c4 + 1] = bf2f(vv.y);
  vs[r][c4 + 2] = bf2f(vv.z); vs[r][c4 + 3] = bf2f(vv.w);
  __syncthreads();
  const int dg = t & 15;
  float a0 = 0.f, a1 = 0.f, a2 = 0.f, a3 = 0.f;
  #pragma unroll 8
  for (int e2 = 0; e2 < 64; e2++){
    float vvv = vs[r][e2];
    float4 m4 = *(const float4*)&Ms[e2 * 64 + dg * 4];
    a0 += vvv * m4.x; a1 += vvv * m4.y; a2 += vvv * m4.z; a3 += vvv * m4.w;
  }
  // reshape: flat = h*N*64 + n*64 + d  -> row = h*1024 + n/4, col = (n&3)*64 + d
  int orow = b * NSEQ + h * 1024 + (n >> 2);
  int ocol = (n & 3) * 64 + dg * 4;
  ushort4 o; o.x = f2bf(a0); o.y = f2bf(a1); o.z = f2bf(a2); o.w = f2bf(a3);
  *(ushort4*)(attn + (size_t)orow * 256 + ocol) = o;
}

// ---------------- h = x + LN(LN(y1, g_ao, be_ao), g1, be1); also h in bf16 ----------------
__global__ void k_ln_a(const float* __restrict__ y1, const float* __restrict__ x,
                       const float* __restrict__ g_ao, const float* __restrict__ be_ao,
                       const float* __restrict__ g1, const float* __restrict__ be1,
                       float* __restrict__ h, unsigned short* __restrict__ hbf)
{
  const int t = threadIdx.x;
  const int row = blockIdx.x * 4 + (t >> 6);
  const int l = t & 63;
  const size_t off = (size_t)row * 256 + l * 4;
  float4 v = *(const float4*)(y1 + off);
  float mu = wsum(v.x + v.y + v.z + v.w) * 0.00390625f;
  float dx = v.x - mu, dy = v.y - mu, dz = v.z - mu, dw = v.w - mu;
  float rstd = rsqrtf(wsum(dx*dx + dy*dy + dz*dz + dw*dw) * 0.00390625f + EPSF);
  float4 ga = *(const float4*)(g_ao + l * 4);
  float4 ba = *(const float4*)(be_ao + l * 4);
  float zx = dx * rstd * ga.x + ba.x, zy = dy * rstd * ga.y + ba.y;
  float zz = dz * rstd * ga.z + ba.z, zw = dw * rstd * ga.w + ba.w;
  float mu2 = wsum(zx + zy + zz + zw) * 0.00390625f;
  float ex = zx - mu2, ey = zy - mu2, ez = zz - mu2, ew = zw - mu2;
  float rstd2 = rsqrtf(wsum(ex*ex + ey*ey + ez*ez + ew*ew) * 0.00390625f + EPSF);
  float4 gb = *(const float4*)(g1 + l * 4);
  float4 bb = *(const float4*)(be1 + l * 4);
  float4 xr = *(const float4*)(x + off);
  float hx = xr.x + ex * rstd2 * gb.x + bb.x;
  float hy = xr.y + ey * rstd2 * gb.y + bb.y;
  float hz = xr.z + ez * rstd2 * gb.z + bb.z;
  float hw = xr.w + ew * rstd2 * gb.w + bb.w;
  float4 hv = {hx, hy, hz, hw};
  *(float4*)(h + off) = hv;
  ushort4 hb; hb.x = f2bf(hx); hb.y = f2bf(hy); hb.z = f2bf(hz); hb.w = f2bf(hw);
  *(ushort4*)(hbf + off) = hb;
}

// ---------------- out = x + h + LN(mlp2, g2, be2) ----------------
__global__ void k_ln_b(const float* __restrict__ mlp2, const float* __restrict__ x,
                       const float* __restrict__ h,
                       const float* __restrict__ g2, const float* __restrict__ be2,
                       float* __restrict__ out)
{
  const int t = threadIdx.x;
  const int row = blockIdx.x * 4 + (t >> 6);
  const int l = t & 63;
  const size_t off = (size_t)row * 256 + l * 4;
  float4 v = *(const float4*)(mlp2 + off);
  float mu = wsum(v.x + v.y + v.z + v.w) * 0.00390625f;
  float dx = v.x - mu, dy = v.y - mu, dz = v.z - mu, dw = v.w - mu;
  float rstd = rsqrtf(wsum(dx*dx + dy*dy + dz*dz + dw*dw) * 0.00390625f + EPSF);
  float4 g = *(const float4*)(g2 + l * 4);
  float4 be = *(const float4*)(be2 + l * 4);
  float4 xr = *(const float4*)(x + off);
  float4 hr = *(const float4*)(h + off);
  float4 o;
  o.x = xr.x + hr.x + dx * rstd * g.x + be.x;
  o.y = xr.y + hr.y + dy * rstd * g.y + be.y;
  o.z = xr.z + hr.z + dz * rstd * g.z + be.z;
  o.w = xr.w + hr.w + dw * rstd * g.w + be.w;
  *(float4*)(out + off) = o;
}

extern "C" void kernel_launch(void* const* d_in, const int* in_sizes, int n_in,
                              void* d_out, int out_size, void* d_ws, size_t ws_size,
                              hipStream_t stream)
{
  const float* x     = (const float*)d_in[0];
  const float* w_qkv = (const float*)d_in[1];
  const float* w_ao  = (const float*)d_in[2];
  const float* b_ao  = (const float*)d_in[3];
  const float* g_ao  = (const float*)d_in[4];
  const float* be_ao = (const float*)d_in[5];
  const float* g1    = (const float*)d_in[6];
  const float* be1   = (const float*)d_in[7];
  const float* w_fc1 = (const float*)d_in[8];
  const float* b_fc1 = (const float*)d_in[9];
  const float* w_fc2 = (const float*)d_in[10];
  const float* b_fc2 = (const float*)d_in[11];
  const float* g2    = (const float*)d_in[12];
  const float* be2   = (const float*)d_in[13];
  float* out = (float*)d_out;
  char* ws = (char*)d_ws;

  unsigned short* qkv   = (unsigned short*)(ws + 0);          // [8192][768] bf16
  unsigned short* xbf   = (unsigned short*)(ws + 12582912);   // [8192][256] bf16; reused as h_bf16
  unsigned short* wqkvT = (unsigned short*)(ws + 16777216);   // [768][256]
  unsigned short* waoT  = (unsigned short*)(ws + 17170432);   // [256][256]
  unsigned short* wfc1T = (unsigned short*)(ws + 17301504);   // [1024][256]
  unsigned short* wfc2T = (unsigned short*)(ws + 17825792);   // [256][1024]
  float* kmaxb = (float*)(ws + 18350080);                     // [512]
  float* kinvb = (float*)(ws + 18352128);                     // [512]
  float* Mpart = (float*)(ws + 18354176);                     // [16][8][64][64]
  float* Mm    = (float*)(ws + 20451328);                     // [8][64][64]
  unsigned short* attn = (unsigned short*)(ws + 20582400);    // [8192][256] bf16
  float* y1    = (float*)(ws + 24776704);                     // [8192][256] f32; reused as mlp2
  float* hbuf  = (float*)(ws + 33165312);                     // [8192][256] f32
  unsigned short* mlp1 = (unsigned short*)(ws + 41553920);    // [8192][1024] bf16

  k_f2bf<<<2048, 256, 0, stream>>>(x, xbf, R_TOT * 256);
  k_transpose_bf<<<768,  256, 0, stream>>>(w_qkv, wqkvT, 256, 768);
  k_transpose_bf<<<256,  256, 0, stream>>>(w_ao,  waoT,  256, 256);
  k_transpose_bf<<<1024, 256, 0, stream>>>(w_fc1, wfc1T, 256, 1024);
  k_transpose_bf<<<1024, 256, 0, stream>>>(w_fc2, wfc2T, 1024, 256);

  // qkv = x @ w_qkv (no bias), bf16 out
  k_gemm<false, false, true><<<dim3(6, 64), 256, 0, stream>>>(
      xbf, wqkvT, nullptr, nullptr, qkv, R_TOT, 768, 256);

  k_smax<<<512, 256, 0, stream>>>(qkv, kmaxb, kinvb);
  k_mpart<<<dim3(16, 8), 256, 0, stream>>>(qkv, kmaxb, kinvb, Mpart);
  k_mreduce<<<128, 256, 0, stream>>>(Mpart, Mm);
  k_vm<<<dim3(256, 8), 256, 0, stream>>>(qkv, Mm, attn);

  // y1 = attn @ w_ao + b_ao (f32 out)
  k_gemm<true, false, false><<<dim3(2, 64), 256, 0, stream>>>(
      attn, waoT, b_ao, y1, nullptr, R_TOT, 256, 256);

  k_ln_a<<<2048, 256, 0, stream>>>(y1, x, g_ao, be_ao, g1, be1, hbuf, xbf);

  // mlp1 = gelu(h @ w_fc1 + b_fc1), bf16 out
  k_gemm<true, true, true><<<dim3(8, 64), 256, 0, stream>>>(
      xbf, wfc1T, b_fc1, nullptr, mlp1, R_TOT, 1024, 256);

  // mlp2 = mlp1 @ w_fc2 + b_fc2 (f32 out)
  k_gemm<true, false, false><<<dim3(2, 64), 256, 0, stream>>>(
      mlp1, wfc2T, b_fc2, y1, nullptr, R_TOT, 256, 1024);

  k_ln_b<<<2048, 256, 0, stream>>>(y1, x, hbuf, g2, be2, out);
}

// Round 2
// 117.162 us; speedup vs baseline: 1.2621x; 1.2621x over previous
//
#include <hip/hip_runtime.h>

typedef __attribute__((ext_vector_type(8))) short short8;
typedef __attribute__((ext_vector_type(4))) float f32x4;

#define EPSF 1e-5f
#define NSEQ 4096
#define R_TOT 8192

__device__ __forceinline__ float bf2f(unsigned short u){
  union { unsigned int i; float f; } v; v.i = ((unsigned int)u) << 16; return v.f;
}
__device__ __forceinline__ unsigned short f2bf(float f){
  union { float f; unsigned int i; } v; v.f = f;
  unsigned int u = v.i;
  u += 0x7FFFu + ((u >> 16) & 1u);          // RNE
  return (unsigned short)(u >> 16);
}
__device__ __forceinline__ float wsum(float v){
  #pragma unroll
  for (int o = 32; o > 0; o >>= 1) v += __shfl_xor(v, o, 64);
  return v;
}
__device__ __forceinline__ float gelu_tanh(float x){
  float x3 = x * x * x;
  return 0.5f * x * (1.0f + tanhf(0.7978845608028654f * (x + 0.044715f * x3)));
}
__device__ __forceinline__ void gload_lds16(const unsigned short* g, unsigned short* l){
  __builtin_amdgcn_global_load_lds(
      (const __attribute__((address_space(1))) unsigned int*)g,
      (__attribute__((address_space(3))) unsigned int*)l, 16, 0, 0);
}

// ---------------- fp32 -> bf16 convert (vectorized) ----------------
__global__ void k_f2bf(const float* __restrict__ in, unsigned short* __restrict__ out, int n){
  int i = (blockIdx.x * 256 + threadIdx.x) * 4;
  if (i < n){
    float4 v = *(const float4*)(in + i);
    ushort4 o;
    o.x = f2bf(v.x); o.y = f2bf(v.y); o.z = f2bf(v.z); o.w = f2bf(v.w);
    *(ushort4*)(out + i) = o;
  }
}

// ---------------- all 4 weight transposes, LDS-tiled, coalesced both sides ----------------
__global__ void k_wT(const float* __restrict__ w_qkv, const float* __restrict__ w_ao,
                     const float* __restrict__ w_fc1, const float* __restrict__ w_fc2,
                     unsigned short* __restrict__ oq, unsigned short* __restrict__ oa,
                     unsigned short* __restrict__ o1, unsigned short* __restrict__ o2)
{
  int bid = blockIdx.x;
  const float* in; unsigned short* out; int rows, cols, tid;
  if (bid < 48)      { in = w_qkv; out = oq; rows = 256;  cols = 768;  tid = bid; }
  else if (bid < 64) { in = w_ao;  out = oa; rows = 256;  cols = 256;  tid = bid - 48; }
  else if (bid < 128){ in = w_fc1; out = o1; rows = 256;  cols = 1024; tid = bid - 64; }
  else               { in = w_fc2; out = o2; rows = 1024; cols = 256;  tid = bid - 128; }
  const int tC = cols >> 6;
  const int r0 = (tid / tC) * 64, c0 = (tid % tC) * 64;
  __shared__ float tile[64][68];
  const int t = threadIdx.x;
  const int i = t >> 4, j4 = (t & 15) * 4;
  #pragma unroll
  for (int p = 0; p < 4; p++){
    float4 v = *(const float4*)(in + (size_t)(r0 + i + p * 16) * cols + c0 + j4);
    tile[i + p * 16][j4 + 0] = v.x; tile[i + p * 16][j4 + 1] = v.y;
    tile[i + p * 16][j4 + 2] = v.z; tile[i + p * 16][j4 + 3] = v.w;
  }
  __syncthreads();
  #pragma unroll
  for (int p = 0; p < 4; p++){
    int ci = i + p * 16;
    ushort4 o;
    o.x = f2bf(tile[j4 + 0][ci]); o.y = f2bf(tile[j4 + 1][ci]);
    o.z = f2bf(tile[j4 + 2][ci]); o.w = f2bf(tile[j4 + 3][ci]);
    *(ushort4*)(out + (size_t)(c0 + ci) * rows + r0 + j4) = o;
  }
}

// ---------------- bf16 MFMA GEMM: C[M,N] = A[M,K] @ BT[N,K]^T ----------------
// global_load_lds(16B) staging into linear [BM][64]/[BN][64] LDS (m97 pattern).
template<int BM, int BN, bool HAS_BIAS, bool DO_GELU, bool OUT_BF16>
__global__ __launch_bounds__(256) void k_gemm(const unsigned short* __restrict__ A,
                       const unsigned short* __restrict__ BT,
                       const float* __restrict__ bias,
                       float* __restrict__ Cf,
                       unsigned short* __restrict__ Cb,
                       int M, int N, int K)
{
  constexpr int BK = 64;
  constexpr int FM = BM / 32, FN = BN / 32;
  __shared__ unsigned short As[BM * BK];
  __shared__ unsigned short Bs[BN * BK];
  const int t  = threadIdx.x;
  const int l  = t & 63;
  const int w  = t >> 6;
  const int wm = w >> 1, wn = w & 1;
  const int lr = l & 15, kq = l >> 4;
  const int m0 = blockIdx.y * BM, n0 = blockIdx.x * BN;

  f32x4 acc[FM][FN];
  #pragma unroll
  for (int i = 0; i < FM; i++)
    #pragma unroll
    for (int j = 0; j < FN; j++) acc[i][j] = (f32x4){0.f, 0.f, 0.f, 0.f};

  // staging coords: chunk = 1024 B = 8 rows of 64 bf16; lane l -> row l/8, colE (l&7)*8
  const int crow = l >> 3, ccolE = (l & 7) * 8;

  for (int k0 = 0; k0 < K; k0 += BK){
    #pragma unroll
    for (int c = w; c < BM / 8; c += 4)
      gload_lds16(A  + (size_t)(m0 + c * 8 + crow) * K + k0 + ccolE, As + c * 512);
    #pragma unroll
    for (int c = w; c < BN / 8; c += 4)
      gload_lds16(BT + (size_t)(n0 + c * 8 + crow) * K + k0 + ccolE, Bs + c * 512);
    __syncthreads();
    #pragma unroll
    for (int kk = 0; kk < BK; kk += 32){
      short8 af[FM], bfr[FN];
      #pragma unroll
      for (int i = 0; i < FM; i++)
        af[i]  = *(const short8*)&As[(wm * (BM / 2) + i * 16 + lr) * 64 + kk + kq * 8];
      #pragma unroll
      for (int j = 0; j < FN; j++)
        bfr[j] = *(const short8*)&Bs[(wn * (BN / 2) + j * 16 + lr) * 64 + kk + kq * 8];
      #pragma unroll
      for (int i = 0; i < FM; i++)
        #pragma unroll
        for (int j = 0; j < FN; j++)
          acc[i][j] = __builtin_amdgcn_mfma_f32_16x16x32_bf16(af[i], bfr[j], acc[i][j], 0, 0, 0);
    }
    __syncthreads();
  }

  const int row0 = m0 + wm * (BM / 2);
  const int col0 = n0 + wn * (BN / 2);
  #pragma unroll
  for (int i = 0; i < FM; i++){
    #pragma unroll
    for (int j = 0; j < FN; j++){
      #pragma unroll
      for (int r = 0; r < 4; r++){
        int row = row0 + i * 16 + kq * 4 + r;
        int col = col0 + j * 16 + lr;
        float v = acc[i][j][r];
        if (HAS_BIAS) v += bias[col];
        if (DO_GELU)  v = gelu_tanh(v);
        if (OUT_BF16) Cb[(size_t)row * N + col] = f2bf(v);
        else          Cf[(size_t)row * N + col] = v;
      }
    }
  }
}

// ---------------- S partials: S[e,d] = sum_n exp(k[n,e]) * q[n,d]; d[e] = sum_n exp(k[n,e]) ----
// (no max-shift needed: k ~ N(0,1) bounded, exp() safe in f32)
__global__ void k_mpart(const unsigned short* __restrict__ qkv,
                        float* __restrict__ Spart, float* __restrict__ dpart)
{
  const int s  = blockIdx.x;   // k-slice 0..15 (256 rows each)
  const int bh = blockIdx.y;   // 0..7
  const int b = bh >> 2, h = bh & 3;
  const int t = threadIdx.x;
  __shared__ float ks[16][64], qs[16][64];
  const int e = t & 63, dg = t >> 6;        // thread computes S[e][dg*16 .. dg*16+15]
  const int r = t >> 4, c4 = (t & 15) * 4;  // staging coords
  float acc[16];
  #pragma unroll
  for (int i = 0; i < 16; i++) acc[i] = 0.f;
  float dsum = 0.f;

  for (int ch = 0; ch < 16; ch++){
    int n = s * 256 + ch * 16 + r;
    const unsigned short* rowp = qkv + (size_t)(b * NSEQ + n) * 768 + h * 64 + c4;
    ushort4 qv = *(const ushort4*)(rowp);
    ushort4 kv = *(const ushort4*)(rowp + 256);
    __syncthreads();            // prev accumulate done
    qs[r][c4 + 0] = bf2f(qv.x); qs[r][c4 + 1] = bf2f(qv.y);
    qs[r][c4 + 2] = bf2f(qv.z); qs[r][c4 + 3] = bf2f(qv.w);
    ks[r][c4 + 0] = expf(bf2f(kv.x)); ks[r][c4 + 1] = expf(bf2f(kv.y));
    ks[r][c4 + 2] = expf(bf2f(kv.z)); ks[r][c4 + 3] = expf(bf2f(kv.w));
    __syncthreads();
    #pragma unroll
    for (int rr = 0; rr < 16; rr++){
      float kvv = ks[rr][e];
      if (dg == 0) dsum += kvv;
      const float4* qp = (const float4*)&qs[rr][dg * 16];
      float4 q0 = qp[0], q1 = qp[1], q2 = qp[2], q3 = qp[3];
      acc[0]  += kvv * q0.x; acc[1]  += kvv * q0.y; acc[2]  += kvv * q0.z; acc[3]  += kvv * q0.w;
      acc[4]  += kvv * q1.x; acc[5]  += kvv * q1.y; acc[6]  += kvv * q1.z; acc[7]  += kvv * q1.w;
      acc[8]  += kvv * q2.x; acc[9]  += kvv * q2.y; acc[10] += kvv * q2.z; acc[11] += kvv * q2.w;
      acc[12] += kvv * q3.x; acc[13] += kvv * q3.y; acc[14] += kvv * q3.z; acc[15] += kvv * q3.w;
    }
  }
  float* outp = Spart + (size_t)(s * 8 + bh) * 4096 + e * 64 + dg * 16;
  #pragma unroll
  for (int i = 0; i < 16; i++) outp[i] = acc[i];
  if (dg == 0) dpart[(s * 8 + bh) * 64 + e] = dsum;
}

// ---------------- reduce 16 K-slices, divide by denom, apply SCALE=0.125 ----------------
__global__ void k_mreduce(const float* __restrict__ Spart, const float* __restrict__ dpart,
                          float* __restrict__ M){
  int idx = blockIdx.x * 256 + threadIdx.x;   // [0, 8*4096)
  int bh = idx >> 12;
  int e  = (idx >> 6) & 63;
  float s = 0.f, dn = 0.f;
  #pragma unroll
  for (int sl = 0; sl < 16; sl++){
    s  += Spart[(size_t)sl * 32768 + idx];
    dn += dpart[sl * 512 + bh * 64 + e];
  }
  M[idx] = 0.125f * s / dn;
}

// ---------------- out = v @ M, written in the torch-reshape layout, bf16 ----------------
__global__ void k_vm(const unsigned short* __restrict__ qkv,
                     const float* __restrict__ M,
                     unsigned short* __restrict__ attn)
{
  const int bh = blockIdx.y, b = bh >> 2, h = bh & 3;
  const int t = threadIdx.x;
  __shared__ float Ms[64 * 64];
  __shared__ float vs[16][64];
  #pragma unroll
  for (int i = 0; i < 16; i++) Ms[i * 256 + t] = M[(size_t)bh * 4096 + i * 256 + t];
  const int r = t >> 4, c4 = (t & 15) * 4;
  const int n = blockIdx.x * 16 + r;
  const unsigned short* vp = qkv + (size_t)(b * NSEQ + n) * 768 + 512 + h * 64 + c4;
  ushort4 vv = *(const ushort4*)vp;
  vs[r][c4 + 0] = bf2f(vv.x); vs[r][c4 + 1] = bf2f(vv.y);
  vs[r][c4 + 2] = bf2f(vv.z); vs[r][c4 + 3] = bf2f(vv.w);
  __syncthreads();
  const int dg = t & 15;
  float a0 = 0.f, a1 = 0.f, a2 = 0.f, a3 = 0.f;
  #pragma unroll 8
  for (int e2 = 0; e2 < 64; e2++){
    float vvv = vs[r][e2];
    float4 m4 = *(const float4*)&Ms[e2 * 64 + dg * 4];
    a0 += vvv * m4.x; a1 += vvv * m4.y; a2 += vvv * m4.z; a3 += vvv * m4.w;
  }
  // reshape: flat = h*N*64 + n*64 + d  -> row = h*1024 + n/4, col = (n&3)*64 + d
  int orow = b * NSEQ + h * 1024 + (n >> 2);
  int ocol = (n & 3) * 64 + dg * 4;
  ushort4 o; o.x = f2bf(a0); o.y = f2bf(a1); o.z = f2bf(a2); o.w = f2bf(a3);
  *(ushort4*)(attn + (size_t)orow * 256 + ocol) = o;
}

// ---------------- h = x + LN(LN(y1, g_ao, be_ao), g1, be1); h f32 + bf16 ----------------
__global__ void k_ln_a(const float* __restrict__ y1, const float* __restrict__ x,
                       const float* __restrict__ g_ao, const float* __restrict__ be_ao,
                       const float* __restrict__ g1, const float* __restrict__ be1,
                       float* __restrict__ h, unsigned short* __restrict__ hbf)
{
  const int t = threadIdx.x;
  const int row = blockIdx.x * 4 + (t >> 6);
  const int l = t & 63;
  const size_t off = (size_t)row * 256 + l * 4;
  float4 v = *(const float4*)(y1 + off);
  float mu = wsum(v.x + v.y + v.z + v.w) * 0.00390625f;
  float dx = v.x - mu, dy = v.y - mu, dz = v.z - mu, dw = v.w - mu;
  float rstd = rsqrtf(wsum(dx*dx + dy*dy + dz*dz + dw*dw) * 0.00390625f + EPSF);
  float4 ga = *(const float4*)(g_ao + l * 4);
  float4 ba = *(const float4*)(be_ao + l * 4);
  float zx = dx * rstd * ga.x + ba.x, zy = dy * rstd * ga.y + ba.y;
  float zz = dz * rstd * ga.z + ba.z, zw = dw * rstd * ga.w + ba.w;
  float mu2 = wsum(zx + zy + zz + zw) * 0.00390625f;
  float ex = zx - mu2, ey = zy - mu2, ez = zz - mu2, ew = zw - mu2;
  float rstd2 = rsqrtf(wsum(ex*ex + ey*ey + ez*ez + ew*ew) * 0.00390625f + EPSF);
  float4 gb = *(const float4*)(g1 + l * 4);
  float4 bb = *(const float4*)(be1 + l * 4);
  float4 xr = *(const float4*)(x + off);
  float hx = xr.x + ex * rstd2 * gb.x + bb.x;
  float hy = xr.y + ey * rstd2 * gb.y + bb.y;
  float hz = xr.z + ez * rstd2 * gb.z + bb.z;
  float hw = xr.w + ew * rstd2 * gb.w + bb.w;
  float4 hv = {hx, hy, hz, hw};
  *(float4*)(h + off) = hv;
  ushort4 hb; hb.x = f2bf(hx); hb.y = f2bf(hy); hb.z = f2bf(hz); hb.w = f2bf(hw);
  *(ushort4*)(hbf + off) = hb;
}

// ---------------- out = x + h + LN(mlp2, g2, be2) ----------------
__global__ void k_ln_b(const float* __restrict__ mlp2, const float* __restrict__ x,
                       const float* __restrict__ h,
                       const float* __restrict__ g2, const float* __restrict__ be2,
                       float* __restrict__ out)
{
  const int t = threadIdx.x;
  const int row = blockIdx.x * 4 + (t >> 6);
  const int l = t & 63;
  const size_t off = (size_t)row * 256 + l * 4;
  float4 v = *(const float4*)(mlp2 + off);
  float mu = wsum(v.x + v.y + v.z + v.w) * 0.00390625f;
  float dx = v.x - mu, dy = v.y - mu, dz = v.z - mu, dw = v.w - mu;
  float rstd = rsqrtf(wsum(dx*dx + dy*dy + dz*dz + dw*dw) * 0.00390625f + EPSF);
  float4 g = *(const float4*)(g2 + l * 4);
  float4 be = *(const float4*)(be2 + l * 4);
  float4 xr = *(const float4*)(x + off);
  float4 hr = *(const float4*)(h + off);
  float4 o;
  o.x = xr.x + hr.x + dx * rstd * g.x + be.x;
  o.y = xr.y + hr.y + dy * rstd * g.y + be.y;
  o.z = xr.z + hr.z + dz * rstd * g.z + be.z;
  o.w = xr.w + hr.w + dw * rstd * g.w + be.w;
  *(float4*)(out + off) = o;
}

extern "C" void kernel_launch(void* const* d_in, const int* in_sizes, int n_in,
                              void* d_out, int out_size, void* d_ws, size_t ws_size,
                              hipStream_t stream)
{
  const float* x     = (const float*)d_in[0];
  const float* w_qkv = (const float*)d_in[1];
  const float* w_ao  = (const float*)d_in[2];
  const float* b_ao  = (const float*)d_in[3];
  const float* g_ao  = (const float*)d_in[4];
  const float* be_ao = (const float*)d_in[5];
  const float* g1    = (const float*)d_in[6];
  const float* be1   = (const float*)d_in[7];
  const float* w_fc1 = (const float*)d_in[8];
  const float* b_fc1 = (const float*)d_in[9];
  const float* w_fc2 = (const float*)d_in[10];
  const float* b_fc2 = (const float*)d_in[11];
  const float* g2    = (const float*)d_in[12];
  const float* be2   = (const float*)d_in[13];
  float* out = (float*)d_out;
  char* ws = (char*)d_ws;

  unsigned short* qkv   = (unsigned short*)(ws + 0);          // [8192][768] bf16
  unsigned short* xbf   = (unsigned short*)(ws + 12582912);   // [8192][256] bf16; reused as h_bf16
  unsigned short* wqkvT = (unsigned short*)(ws + 16777216);   // [768][256]
  unsigned short* waoT  = (unsigned short*)(ws + 17170432);   // [256][256]
  unsigned short* wfc1T = (unsigned short*)(ws + 17301504);   // [1024][256]
  unsigned short* wfc2T = (unsigned short*)(ws + 17825792);   // [256][1024]
  float* Spart = (float*)(ws + 18350080);                     // [16][8][64][64]
  float* dpart = (float*)(ws + 20447232);                     // [16][8][64]
  float* Mm    = (float*)(ws + 20480000);                     // [8][64][64]
  unsigned short* attn = (unsigned short*)(ws + 20611072);    // [8192][256] bf16
  float* y1    = (float*)(ws + 24805376);                     // [8192][256] f32; reused as mlp2
  float* hbuf  = (float*)(ws + 33193984);                     // [8192][256] f32
  unsigned short* mlp1 = (unsigned short*)(ws + 41582592);    // [8192][1024] bf16

  k_f2bf<<<2048, 256, 0, stream>>>(x, xbf, R_TOT * 256);
  k_wT<<<192, 256, 0, stream>>>(w_qkv, w_ao, w_fc1, w_fc2, wqkvT, waoT, wfc1T, wfc2T);

  // qkv = x @ w_qkv (no bias), bf16 out
  k_gemm<128, 128, false, false, true><<<dim3(6, 64), 256, 0, stream>>>(
      xbf, wqkvT, nullptr, nullptr, qkv, R_TOT, 768, 256);

  k_mpart<<<dim3(16, 8), 256, 0, stream>>>(qkv, Spart, dpart);
  k_mreduce<<<128, 256, 0, stream>>>(Spart, dpart, Mm);
  k_vm<<<dim3(256, 8), 256, 0, stream>>>(qkv, Mm, attn);

  // y1 = attn @ w_ao + b_ao (f32 out) — 64x128 tile for 256-block parallelism
  k_gemm<64, 128, true, false, false><<<dim3(2, 128), 256, 0, stream>>>(
      attn, waoT, b_ao, y1, nullptr, R_TOT, 256, 256);

  k_ln_a<<<2048, 256, 0, stream>>>(y1, x, g_ao, be_ao, g1, be1, hbuf, xbf);

  // mlp1 = gelu(h @ w_fc1 + b_fc1), bf16 out
  k_gemm<128, 128, true, true, true><<<dim3(8, 64), 256, 0, stream>>>(
      xbf, wfc1T, b_fc1, nullptr, mlp1, R_TOT, 1024, 256);

  // mlp2 = mlp1 @ w_fc2 + b_fc2 (f32 out)
  k_gemm<64, 128, true, false, false><<<dim3(2, 128), 256, 0, stream>>>(
      mlp1, wfc2T, b_fc2, y1, nullptr, R_TOT, 256, 1024);

  k_ln_b<<<2048, 256, 0, stream>>>(y1, x, hbuf, g2, be2, out);
}

// Round 3
// 100.181 us; speedup vs baseline: 1.4760x; 1.1695x over previous
//
#include <hip/hip_runtime.h>

typedef __attribute__((ext_vector_type(8))) short short8;
typedef __attribute__((ext_vector_type(4))) float f32x4;

#define EPSF 1e-5f
#define NSEQ 4096
#define R_TOT 8192

__device__ __forceinline__ float bf2f(unsigned short u){
  union { unsigned int i; float f; } v; v.i = ((unsigned int)u) << 16; return v.f;
}
__device__ __forceinline__ unsigned short f2bf(float f){
  union { float f; unsigned int i; } v; v.f = f;
  unsigned int u = v.i;
  u += 0x7FFFu + ((u >> 16) & 1u);          // RNE
  return (unsigned short)(u >> 16);
}
__device__ __forceinline__ float wsum(float v){
  #pragma unroll
  for (int o = 32; o > 0; o >>= 1) v += __shfl_xor(v, o, 64);
  return v;
}
__device__ __forceinline__ float gelu_tanh(float x){
  float x3 = x * x * x;
  return 0.5f * x * (1.0f + tanhf(0.7978845608028654f * (x + 0.044715f * x3)));
}
__device__ __forceinline__ void gload_lds16(const unsigned short* g, unsigned short* l){
  __builtin_amdgcn_global_load_lds(
      (const __attribute__((address_space(1))) unsigned int*)g,
      (__attribute__((address_space(3))) unsigned int*)l, 16, 0, 0);
}

// ---------------- prep: x->bf16 (blocks 0..2047) + 4 weight transposes (2048..2239) ----
__global__ void k_prep(const float* __restrict__ x, unsigned short* __restrict__ xbf,
                       const float* __restrict__ w_qkv, const float* __restrict__ w_ao,
                       const float* __restrict__ w_fc1, const float* __restrict__ w_fc2,
                       unsigned short* __restrict__ oq, unsigned short* __restrict__ oa,
                       unsigned short* __restrict__ o1, unsigned short* __restrict__ o2)
{
  int bid = blockIdx.x;
  const int t = threadIdx.x;
  if (bid < 2048){
    int i = (bid * 256 + t) * 4;
    float4 v = *(const float4*)(x + i);
    ushort4 o;
    o.x = f2bf(v.x); o.y = f2bf(v.y); o.z = f2bf(v.z); o.w = f2bf(v.w);
    *(ushort4*)(xbf + i) = o;
    return;
  }
  bid -= 2048;
  const float* in; unsigned short* out; int rows, cols, tid;
  if (bid < 48)      { in = w_qkv; out = oq; rows = 256;  cols = 768;  tid = bid; }
  else if (bid < 64) { in = w_ao;  out = oa; rows = 256;  cols = 256;  tid = bid - 48; }
  else if (bid < 128){ in = w_fc1; out = o1; rows = 256;  cols = 1024; tid = bid - 64; }
  else               { in = w_fc2; out = o2; rows = 1024; cols = 256;  tid = bid - 128; }
  const int tC = cols >> 6;
  const int r0 = (tid / tC) * 64, c0 = (tid % tC) * 64;
  __shared__ float tile[64][68];
  const int i = t >> 4, j4 = (t & 15) * 4;
  #pragma unroll
  for (int p = 0; p < 4; p++){
    float4 v = *(const float4*)(in + (size_t)(r0 + i + p * 16) * cols + c0 + j4);
    tile[i + p * 16][j4 + 0] = v.x; tile[i + p * 16][j4 + 1] = v.y;
    tile[i + p * 16][j4 + 2] = v.z; tile[i + p * 16][j4 + 3] = v.w;
  }
  __syncthreads();
  #pragma unroll
  for (int p = 0; p < 4; p++){
    int ci = i + p * 16;
    ushort4 o;
    o.x = f2bf(tile[j4 + 0][ci]); o.y = f2bf(tile[j4 + 1][ci]);
    o.z = f2bf(tile[j4 + 2][ci]); o.w = f2bf(tile[j4 + 3][ci]);
    *(ushort4*)(out + (size_t)(c0 + ci) * rows + r0 + j4) = o;
  }
}

// ---------------- bf16 MFMA GEMM: C[M,N] = A[M,K] @ BT[N,K]^T (m97 pattern) ----------
template<int BM, int BN, bool HAS_BIAS, bool DO_GELU, bool OUT_BF16>
__global__ __launch_bounds__(256) void k_gemm(const unsigned short* __restrict__ A,
                       const unsigned short* __restrict__ BT,
                       const float* __restrict__ bias,
                       float* __restrict__ Cf,
                       unsigned short* __restrict__ Cb,
                       int M, int N, int K)
{
  constexpr int BK = 64;
  constexpr int FM = BM / 32, FN = BN / 32;
  __shared__ unsigned short As[BM * BK];
  __shared__ unsigned short Bs[BN * BK];
  const int t  = threadIdx.x;
  const int l  = t & 63;
  const int w  = t >> 6;
  const int wm = w >> 1, wn = w & 1;
  const int lr = l & 15, kq = l >> 4;
  const int m0 = blockIdx.y * BM, n0 = blockIdx.x * BN;

  f32x4 acc[FM][FN];
  #pragma unroll
  for (int i = 0; i < FM; i++)
    #pragma unroll
    for (int j = 0; j < FN; j++) acc[i][j] = (f32x4){0.f, 0.f, 0.f, 0.f};

  const int crow = l >> 3, ccolE = (l & 7) * 8;

  for (int k0 = 0; k0 < K; k0 += BK){
    #pragma unroll
    for (int c = w; c < BM / 8; c += 4)
      gload_lds16(A  + (size_t)(m0 + c * 8 + crow) * K + k0 + ccolE, As + c * 512);
    #pragma unroll
    for (int c = w; c < BN / 8; c += 4)
      gload_lds16(BT + (size_t)(n0 + c * 8 + crow) * K + k0 + ccolE, Bs + c * 512);
    __syncthreads();
    #pragma unroll
    for (int kk = 0; kk < BK; kk += 32){
      short8 af[FM], bfr[FN];
      #pragma unroll
      for (int i = 0; i < FM; i++)
        af[i]  = *(const short8*)&As[(wm * (BM / 2) + i * 16 + lr) * 64 + kk + kq * 8];
      #pragma unroll
      for (int j = 0; j < FN; j++)
        bfr[j] = *(const short8*)&Bs[(wn * (BN / 2) + j * 16 + lr) * 64 + kk + kq * 8];
      #pragma unroll
      for (int i = 0; i < FM; i++)
        #pragma unroll
        for (int j = 0; j < FN; j++)
          acc[i][j] = __builtin_amdgcn_mfma_f32_16x16x32_bf16(af[i], bfr[j], acc[i][j], 0, 0, 0);
    }
    __syncthreads();
  }

  const int row0 = m0 + wm * (BM / 2);
  const int col0 = n0 + wn * (BN / 2);
  #pragma unroll
  for (int i = 0; i < FM; i++){
    #pragma unroll
    for (int j = 0; j < FN; j++){
      #pragma unroll
      for (int r = 0; r < 4; r++){
        int row = row0 + i * 16 + kq * 4 + r;
        int col = col0 + j * 16 + lr;
        float v = acc[i][j][r];
        if (HAS_BIAS) v += bias[col];
        if (DO_GELU)  v = gelu_tanh(v);
        if (OUT_BF16) Cb[(size_t)row * N + col] = f2bf(v);
        else          Cf[(size_t)row * N + col] = v;
      }
    }
  }
}

// ------- fused proj GEMM + double-LN + residual: full-row tile BM=32, BN=256 --------
// y = attn@w_ao + b_ao; z = LN(y)*g_ao+be_ao; e = LN(z)*g1+be1; h = x+e
// writes hbf = bf16(h), sxh = x + h
__global__ __launch_bounds__(256) void k_proj_dln(
    const unsigned short* __restrict__ A, const unsigned short* __restrict__ BT,
    const float* __restrict__ bias, const float* __restrict__ x,
    const float* __restrict__ g_ao, const float* __restrict__ be_ao,
    const float* __restrict__ g1, const float* __restrict__ be1,
    unsigned short* __restrict__ hbf, float* __restrict__ sxh)
{
  constexpr int K = 256;
  __shared__ __align__(16) char smem[36864];
  unsigned short* As = (unsigned short*)smem;            // [32*64]
  unsigned short* Bs = (unsigned short*)(smem + 4096);   // [256*64]
  float* yt = (float*)smem;                              // [32][260] (aliases staging)
  const int t = threadIdx.x, l = t & 63, w = t >> 6;
  const int lr = l & 15, kq = l >> 4;
  const int m0 = blockIdx.x * 32;
  const int crow = l >> 3, ccolE = (l & 7) * 8;
  f32x4 acc[2][4];
  #pragma unroll
  for (int i = 0; i < 2; i++)
    #pragma unroll
    for (int j = 0; j < 4; j++) acc[i][j] = (f32x4){0.f, 0.f, 0.f, 0.f};

  for (int k0 = 0; k0 < K; k0 += 64){
    gload_lds16(A + (size_t)(m0 + w * 8 + crow) * K + k0 + ccolE, As + w * 512);
    #pragma unroll
    for (int c = w; c < 32; c += 4)
      gload_lds16(BT + (size_t)(c * 8 + crow) * K + k0 + ccolE, Bs + c * 512);
    __syncthreads();
    #pragma unroll
    for (int kk = 0; kk < 64; kk += 32){
      short8 af[2], bfr[4];
      #pragma unroll
      for (int i = 0; i < 2; i++)
        af[i] = *(const short8*)&As[(i * 16 + lr) * 64 + kk + kq * 8];
      #pragma unroll
      for (int j = 0; j < 4; j++)
        bfr[j] = *(const short8*)&Bs[(w * 64 + j * 16 + lr) * 64 + kk + kq * 8];
      #pragma unroll
      for (int i = 0; i < 2; i++)
        #pragma unroll
        for (int j = 0; j < 4; j++)
          acc[i][j] = __builtin_amdgcn_mfma_f32_16x16x32_bf16(af[i], bfr[j], acc[i][j], 0, 0, 0);
    }
    __syncthreads();
  }
  #pragma unroll
  for (int i = 0; i < 2; i++)
    #pragma unroll
    for (int j = 0; j < 4; j++){
      float bv = bias[w * 64 + j * 16 + lr];
      #pragma unroll
      for (int r = 0; r < 4; r++)
        yt[(i * 16 + kq * 4 + r) * 260 + w * 64 + j * 16 + lr] = acc[i][j][r] + bv;
    }
  __syncthreads();
  const int gl = t & 63;
  #pragma unroll
  for (int rp = 0; rp < 8; rp++){
    int row = rp * 4 + (t >> 6);
    float4 v = *(const float4*)(yt + row * 260 + gl * 4);
    float mu = wsum(v.x + v.y + v.z + v.w) * 0.00390625f;
    float dx = v.x - mu, dy = v.y - mu, dz = v.z - mu, dw = v.w - mu;
    float rstd = rsqrtf(wsum(dx*dx + dy*dy + dz*dz + dw*dw) * 0.00390625f + EPSF);
    float4 ga = *(const float4*)(g_ao + gl * 4);
    float4 ba = *(const float4*)(be_ao + gl * 4);
    float zx = dx * rstd * ga.x + ba.x, zy = dy * rstd * ga.y + ba.y;
    float zz = dz * rstd * ga.z + ba.z, zw = dw * rstd * ga.w + ba.w;
    float mu2 = wsum(zx + zy + zz + zw) * 0.00390625f;
    float ex = zx - mu2, ey = zy - mu2, ez = zz - mu2, ew = zw - mu2;
    float rstd2 = rsqrtf(wsum(ex*ex + ey*ey + ez*ez + ew*ew) * 0.00390625f + EPSF);
    float4 gb = *(const float4*)(g1 + gl * 4);
    float4 bb = *(const float4*)(be1 + gl * 4);
    size_t off = (size_t)(m0 + row) * 256 + gl * 4;
    float4 xr = *(const float4*)(x + off);
    float hx = xr.x + ex * rstd2 * gb.x + bb.x;
    float hy = xr.y + ey * rstd2 * gb.y + bb.y;
    float hz = xr.z + ez * rstd2 * gb.z + bb.z;
    float hw = xr.w + ew * rstd2 * gb.w + bb.w;
    ushort4 hb; hb.x = f2bf(hx); hb.y = f2bf(hy); hb.z = f2bf(hz); hb.w = f2bf(hw);
    *(ushort4*)(hbf + off) = hb;
    float4 sv = {xr.x + hx, xr.y + hy, xr.z + hz, xr.w + hw};
    *(float4*)(sxh + off) = sv;
  }
}

// ------- fused fc2 GEMM + LN + residual: out = sxh + LN(mlp1@w_fc2+b_fc2)*g2+be2 -----
__global__ __launch_bounds__(256) void k_fc2_ln(
    const unsigned short* __restrict__ A, const unsigned short* __restrict__ BT,
    const float* __restrict__ bias, const float* __restrict__ sxh,
    const float* __restrict__ g2, const float* __restrict__ be2,
    float* __restrict__ out)
{
  constexpr int K = 1024;
  __shared__ __align__(16) char smem[36864];
  unsigned short* As = (unsigned short*)smem;
  unsigned short* Bs = (unsigned short*)(smem + 4096);
  float* yt = (float*)smem;
  const int t = threadIdx.x, l = t & 63, w = t >> 6;
  const int lr = l & 15, kq = l >> 4;
  const int m0 = blockIdx.x * 32;
  const int crow = l >> 3, ccolE = (l & 7) * 8;
  f32x4 acc[2][4];
  #pragma unroll
  for (int i = 0; i < 2; i++)
    #pragma unroll
    for (int j = 0; j < 4; j++) acc[i][j] = (f32x4){0.f, 0.f, 0.f, 0.f};

  for (int k0 = 0; k0 < K; k0 += 64){
    gload_lds16(A + (size_t)(m0 + w * 8 + crow) * K + k0 + ccolE, As + w * 512);
    #pragma unroll
    for (int c = w; c < 32; c += 4)
      gload_lds16(BT + (size_t)(c * 8 + crow) * K + k0 + ccolE, Bs + c * 512);
    __syncthreads();
    #pragma unroll
    for (int kk = 0; kk < 64; kk += 32){
      short8 af[2], bfr[4];
      #pragma unroll
      for (int i = 0; i < 2; i++)
        af[i] = *(const short8*)&As[(i * 16 + lr) * 64 + kk + kq * 8];
      #pragma unroll
      for (int j = 0; j < 4; j++)
        bfr[j] = *(const short8*)&Bs[(w * 64 + j * 16 + lr) * 64 + kk + kq * 8];
      #pragma unroll
      for (int i = 0; i < 2; i++)
        #pragma unroll
        for (int j = 0; j < 4; j++)
          acc[i][j] = __builtin_amdgcn_mfma_f32_16x16x32_bf16(af[i], bfr[j], acc[i][j], 0, 0, 0);
    }
    __syncthreads();
  }
  #pragma unroll
  for (int i = 0; i < 2; i++)
    #pragma unroll
    for (int j = 0; j < 4; j++){
      float bv = bias[w * 64 + j * 16 + lr];
      #pragma unroll
      for (int r = 0; r < 4; r++)
        yt[(i * 16 + kq * 4 + r) * 260 + w * 64 + j * 16 + lr] = acc[i][j][r] + bv;
    }
  __syncthreads();
  const int gl = t & 63;
  #pragma unroll
  for (int rp = 0; rp < 8; rp++){
    int row = rp * 4 + (t >> 6);
    float4 v = *(const float4*)(yt + row * 260 + gl * 4);
    float mu = wsum(v.x + v.y + v.z + v.w) * 0.00390625f;
    float dx = v.x - mu, dy = v.y - mu, dz = v.z - mu, dw = v.w - mu;
    float rstd = rsqrtf(wsum(dx*dx + dy*dy + dz*dz + dw*dw) * 0.00390625f + EPSF);
    float4 g = *(const float4*)(g2 + gl * 4);
    float4 be = *(const float4*)(be2 + gl * 4);
    size_t off = (size_t)(m0 + row) * 256 + gl * 4;
    float4 sv = *(const float4*)(sxh + off);
    float4 o;
    o.x = sv.x + dx * rstd * g.x + be.x;
    o.y = sv.y + dy * rstd * g.y + be.y;
    o.z = sv.z + dz * rstd * g.z + be.z;
    o.w = sv.w + dw * rstd * g.w + be.w;
    *(float4*)(out + off) = o;
  }
}

// ---------------- S partials: S[e,d] = sum_n exp(k[n,e]) * q[n,d]; d[e] = sum exp ----
__global__ void k_mpart(const unsigned short* __restrict__ qkv,
                        float* __restrict__ Spart, float* __restrict__ dpart)
{
  const int s  = blockIdx.x;   // k-slice 0..31 (128 rows each)
  const int bh = blockIdx.y;   // 0..7
  const int b = bh >> 2, h = bh & 3;
  const int t = threadIdx.x;
  __shared__ float ks[16][64], qs[16][64];
  const int e = t & 63, dg = t >> 6;
  const int r = t >> 4, c4 = (t & 15) * 4;
  float acc[16];
  #pragma unroll
  for (int i = 0; i < 16; i++) acc[i] = 0.f;
  float dsum = 0.f;

  for (int ch = 0; ch < 8; ch++){
    int n = s * 128 + ch * 16 + r;
    const unsigned short* rowp = qkv + (size_t)(b * NSEQ + n) * 768 + h * 64 + c4;
    ushort4 qv = *(const ushort4*)(rowp);
    ushort4 kv = *(const ushort4*)(rowp + 256);
    __syncthreads();
    qs[r][c4 + 0] = bf2f(qv.x); qs[r][c4 + 1] = bf2f(qv.y);
    qs[r][c4 + 2] = bf2f(qv.z); qs[r][c4 + 3] = bf2f(qv.w);
    ks[r][c4 + 0] = expf(bf2f(kv.x)); ks[r][c4 + 1] = expf(bf2f(kv.y));
    ks[r][c4 + 2] = expf(bf2f(kv.z)); ks[r][c4 + 3] = expf(bf2f(kv.w));
    __syncthreads();
    #pragma unroll
    for (int rr = 0; rr < 16; rr++){
      float kvv = ks[rr][e];
      if (dg == 0) dsum += kvv;
      const float4* qp = (const float4*)&qs[rr][dg * 16];
      float4 q0 = qp[0], q1 = qp[1], q2 = qp[2], q3 = qp[3];
      acc[0]  += kvv * q0.x; acc[1]  += kvv * q0.y; acc[2]  += kvv * q0.z; acc[3]  += kvv * q0.w;
      acc[4]  += kvv * q1.x; acc[5]  += kvv * q1.y; acc[6]  += kvv * q1.z; acc[7]  += kvv * q1.w;
      acc[8]  += kvv * q2.x; acc[9]  += kvv * q2.y; acc[10] += kvv * q2.z; acc[11] += kvv * q2.w;
      acc[12] += kvv * q3.x; acc[13] += kvv * q3.y; acc[14] += kvv * q3.z; acc[15] += kvv * q3.w;
    }
  }
  float* outp = Spart + (size_t)(s * 8 + bh) * 4096 + e * 64 + dg * 16;
  #pragma unroll
  for (int i = 0; i < 16; i++) outp[i] = acc[i];
  if (dg == 0) dpart[(s * 8 + bh) * 64 + e] = dsum;
}

// ---------------- reduce 32 K-slices, divide by denom, apply SCALE=0.125 -------------
__global__ void k_mreduce(const float* __restrict__ Spart, const float* __restrict__ dpart,
                          float* __restrict__ M){
  int idx = blockIdx.x * 256 + threadIdx.x;   // [0, 8*4096)
  int bh = idx >> 12;
  int e  = (idx >> 6) & 63;
  float s = 0.f, dn = 0.f;
  #pragma unroll
  for (int sl = 0; sl < 32; sl++){
    s  += Spart[(size_t)sl * 32768 + idx];
    dn += dpart[sl * 512 + bh * 64 + e];
  }
  M[idx] = 0.125f * s / dn;
}

// ---------------- out = v @ M, written in the torch-reshape layout, bf16 -------------
__global__ void k_vm(const unsigned short* __restrict__ qkv,
                     const float* __restrict__ M,
                     unsigned short* __restrict__ attn)
{
  const int bh = blockIdx.y, b = bh >> 2, h = bh & 3;
  const int t = threadIdx.x;
  __shared__ float Ms[64 * 64];
  __shared__ float vs[16][64];
  #pragma unroll
  for (int i = 0; i < 16; i++) Ms[i * 256 + t] = M[(size_t)bh * 4096 + i * 256 + t];
  const int r = t >> 4, c4 = (t & 15) * 4;
  const int n = blockIdx.x * 16 + r;
  const unsigned short* vp = qkv + (size_t)(b * NSEQ + n) * 768 + 512 + h * 64 + c4;
  ushort4 vv = *(const ushort4*)vp;
  vs[r][c4 + 0] = bf2f(vv.x); vs[r][c4 + 1] = bf2f(vv.y);
  vs[r][c4 + 2] = bf2f(vv.z); vs[r][c4 + 3] = bf2f(vv.w);
  __syncthreads();
  const int dg = t & 15;
  float a0 = 0.f, a1 = 0.f, a2 = 0.f, a3 = 0.f;
  #pragma unroll 8
  for (int e2 = 0; e2 < 64; e2++){
    float vvv = vs[r][e2];
    float4 m4 = *(const float4*)&Ms[e2 * 64 + dg * 4];
    a0 += vvv * m4.x; a1 += vvv * m4.y; a2 += vvv * m4.z; a3 += vvv * m4.w;
  }
  int orow = b * NSEQ + h * 1024 + (n >> 2);
  int ocol = (n & 3) * 64 + dg * 4;
  ushort4 o; o.x = f2bf(a0); o.y = f2bf(a1); o.z = f2bf(a2); o.w = f2bf(a3);
  *(ushort4*)(attn + (size_t)orow * 256 + ocol) = o;
}

extern "C" void kernel_launch(void* const* d_in, const int* in_sizes, int n_in,
                              void* d_out, int out_size, void* d_ws, size_t ws_size,
                              hipStream_t stream)
{
  const float* x     = (const float*)d_in[0];
  const float* w_qkv = (const float*)d_in[1];
  const float* w_ao  = (const float*)d_in[2];
  const float* b_ao  = (const float*)d_in[3];
  const float* g_ao  = (const float*)d_in[4];
  const float* be_ao = (const float*)d_in[5];
  const float* g1    = (const float*)d_in[6];
  const float* be1   = (const float*)d_in[7];
  const float* w_fc1 = (const float*)d_in[8];
  const float* b_fc1 = (const float*)d_in[9];
  const float* w_fc2 = (const float*)d_in[10];
  const float* b_fc2 = (const float*)d_in[11];
  const float* g2    = (const float*)d_in[12];
  const float* be2   = (const float*)d_in[13];
  float* out = (float*)d_out;
  char* ws = (char*)d_ws;

  unsigned short* qkv   = (unsigned short*)(ws + 0);          // [8192][768] bf16
  unsigned short* xbf   = (unsigned short*)(ws + 12582912);   // [8192][256] bf16; reused as hbf
  unsigned short* wqkvT = (unsigned short*)(ws + 16777216);   // [768][256]
  unsigned short* waoT  = (unsigned short*)(ws + 17170432);   // [256][256]
  unsigned short* wfc1T = (unsigned short*)(ws + 17301504);   // [1024][256]
  unsigned short* wfc2T = (unsigned short*)(ws + 17825792);   // [256][1024]
  float* Spart = (float*)(ws + 18350080);                     // [32][8][64][64]
  float* dpart = (float*)(ws + 22544384);                     // [32][8][64]
  float* Mm    = (float*)(ws + 22609920);                     // [8][64][64]
  unsigned short* attn = (unsigned short*)(ws + 22740992);    // [8192][256] bf16
  float* sxh   = (float*)(ws + 26935296);                     // [8192][256] f32
  unsigned short* mlp1 = (unsigned short*)(ws + 35323904);    // [8192][1024] bf16

  k_prep<<<2240, 256, 0, stream>>>(x, xbf, w_qkv, w_ao, w_fc1, w_fc2,
                                   wqkvT, waoT, wfc1T, wfc2T);

  // qkv = x @ w_qkv (no bias), bf16 out
  k_gemm<128, 128, false, false, true><<<dim3(6, 64), 256, 0, stream>>>(
      xbf, wqkvT, nullptr, nullptr, qkv, R_TOT, 768, 256);

  k_mpart<<<dim3(32, 8), 256, 0, stream>>>(qkv, Spart, dpart);
  k_mreduce<<<128, 256, 0, stream>>>(Spart, dpart, Mm);
  k_vm<<<dim3(256, 8), 256, 0, stream>>>(qkv, Mm, attn);

  // fused: y1 = attn@w_ao + b_ao; h = x + LN(LN(y1)); hbf, sxh = x + h
  k_proj_dln<<<256, 256, 0, stream>>>(attn, waoT, b_ao, x, g_ao, be_ao, g1, be1,
                                      xbf, sxh);

  // mlp1 = gelu(h @ w_fc1 + b_fc1), bf16 out
  k_gemm<128, 128, true, true, true><<<dim3(8, 64), 256, 0, stream>>>(
      xbf, wfc1T, b_fc1, nullptr, mlp1, R_TOT, 1024, 256);

  // fused: out = sxh + LN(mlp1@w_fc2 + b_fc2)
  k_fc2_ln<<<256, 256, 0, stream>>>(mlp1, wfc2T, b_fc2, sxh, g2, be2, out);
}